// Round 9
// baseline (194.740 us; speedup 1.0000x reference)
//
#include <hip/hip_runtime.h>

#define NPTS   32768
#define NCODES 1024
#define DIM    256
#define HWSZ   1024
#define CHW    (DIM*HWSZ)      // 262144
#define QSZ    8388608         // B*C*H*W

typedef __attribute__((ext_vector_type(8))) short short8;    // 8 bf16 = 4 VGPRs
typedef __attribute__((ext_vector_type(16))) float f32x16;   // 32x32 acc tile

// async global->LDS, 16B per lane; dest = wave-uniform base + lane*16
__device__ __forceinline__ void gload16(const void* g, void* l) {
    __builtin_amdgcn_global_load_lds((const __attribute__((address_space(1))) void*)g,
                                     (__attribute__((address_space(3))) void*)l,
                                     16, 0, 0);
}

__device__ __forceinline__ unsigned bf16_rne(float f) {
    unsigned u = __float_as_uint(f);
    return (u + 0x7fffu + ((u >> 16) & 1u)) >> 16;
}

// pack (dist, code) into a monotone u64 key: smaller dist first, then smaller code.
__device__ __forceinline__ unsigned long long pack_di(float d, int code) {
    unsigned u = __float_as_uint(d);
    unsigned key = u ^ ((unsigned)((int)u >> 31) | 0x80000000u);
    return ((unsigned long long)key << 32) | (unsigned)code;
}

// Frag-major layout for 32x32x16 MFMA: frag = 32 rows x 16 k = 1KB.
// element (row n, chan c) -> frag ((n>>5)*16 + (c>>4)), within-frag lane
// = (n&31) + 32*((c>>3)&1), elem = c&7  =>  an operand frag load is
// base + lane*16B, fully contiguous (100% line utilization).
// Operand mapping (analog of verified 16x16: row=lane&15,k=(lane>>4)*8+e):
//   A/B lane l holds [row = l&31][k = (l>>5)*8 + e].
__device__ __forceinline__ int fmoff32(int n, int c) {
    return ((n >> 5) * 16 + (c >> 4)) * 512 + (((c >> 3) & 1) * 32 + (n & 31)) * 8 + (c & 7);
}

// ---- fused prep: blocks 0..2047 = z -> Xh/Xl transpose+split (c-half per block);
//                  blocks 2048..2303 = emb -> Eh/El + e2, plus win[] init ----
__global__ void k_prep(const float* __restrict__ z, const float* __restrict__ emb,
                       short* __restrict__ Xh, short* __restrict__ Xl,
                       short* __restrict__ Eh, short* __restrict__ El,
                       float* __restrict__ e2, unsigned long long* __restrict__ win) {
    int tid = threadIdx.x;
    if (blockIdx.x >= 2048) {
        int eb = blockIdx.x - 2048;
        // init packed-argmin array (runs before k_dist by stream order)
        int widx = eb * 256 + tid;
        if (widx < NPTS) win[widx] = ~0ull;
        // --- emb row -> Eh/El bf16 split + e2 (fp64). 1 wave per row. ---
        int lane = tid & 63, w = tid >> 6;
        int k = eb * 4 + w;
        const float4 v = *reinterpret_cast<const float4*>(emb + k * DIM + lane * 4);
        float f[4] = {v.x, v.y, v.z, v.w};
        short h[4], l[4];
        double s = 0.0;
        #pragma unroll
        for (int i = 0; i < 4; ++i) {
            unsigned hb = bf16_rne(f[i]);
            float hf = __uint_as_float(hb << 16);
            h[i] = (short)hb;
            l[i] = (short)bf16_rne(f[i] - hf);
            s += (double)f[i] * f[i];
        }
        int eoff = fmoff32(k, lane * 4);   // (c&7) in {0,4} -> 8B-aligned
        *reinterpret_cast<short4*>(Eh + eoff) = make_short4(h[0], h[1], h[2], h[3]);
        *reinterpret_cast<short4*>(El + eoff) = make_short4(l[0], l[1], l[2], l[3]);
        #pragma unroll
        for (int m = 32; m >= 1; m >>= 1) s += __shfl_xor(s, m);
        if (lane == 0) e2[k] = (float)s;
        return;
    }
    // --- z (b,c,hw) -> Xh/Xl frag-major bf16 hi/lo; 16B stores ---
    __shared__ float T[64][33];          // [c_local][hw_local], pad: <=2-way banks
    int blk = blockIdx.x;
    int b   = blk >> 6;
    int rem = blk & 63;
    int ht  = rem >> 1;
    int ch  = rem & 1;                   // c-half: cc in {2ch, 2ch+1}
    int hw0 = ht * 32;
    int n0  = b * HWSZ + hw0;
    int hq = tid & 7, cr = tid >> 3;     // read map: 32 c-rows x 8 float4 lanes
    int wp = tid >> 3, wc = tid & 7;     // write map: 32 points x 8 channel-octets
    const float* zp = z + b * CHW;
    #pragma unroll
    for (int cc2 = 0; cc2 < 2; ++cc2) {
        int c0 = (ch * 2 + cc2) * 64;
        if (cc2) __syncthreads();
        #pragma unroll
        for (int p = 0; p < 2; ++p) {
            int c = p * 32 + cr;
            float4 v = *reinterpret_cast<const float4*>(zp + (c0 + c) * HWSZ + hw0 + hq * 4);
            T[c][hq * 4 + 0] = v.x; T[c][hq * 4 + 1] = v.y;
            T[c][hq * 4 + 2] = v.z; T[c][hq * 4 + 3] = v.w;
        }
        __syncthreads();
        short8 hv, lv;
        #pragma unroll
        for (int k = 0; k < 8; ++k) {
            float f = T[wc * 8 + k][wp];
            unsigned hb = bf16_rne(f);
            float hf = __uint_as_float(hb << 16);
            hv[k] = (short)hb;
            lv[k] = (short)bf16_rne(f - hf);
        }
        int off = fmoff32(n0 + wp, c0 + wc * 8);   // octet-aligned -> 16B store
        *reinterpret_cast<short8*>(Xh + off) = hv;
        *reinterpret_cast<short8*>(Xl + off) = lv;
    }
}

// ---- split-mechanism distance GEMM (32x32x16 MFMA) + argmin ----
// Round-14 = Round-13 resubmit (infra failure) + VMEM issue-order hardening:
// sched_barrier(0) between STAGE_B issue and the ah prefetch issue pins the
// order so vmcnt(4) provably completes {al(t), B(t+1)} while leaving only
// {ah(t+1)} in flight across the release barrier. Without the fence the
// scheduler could hoist ah above STAGE_B and the barrier would release
// readers before this wave's B frags landed (cross-wave race).
// Structure: A (X, 33MB, long-latency) direct global->VGPR + 1-step prefetch;
// B (E, 2MB, L2-hot) gload16-staged double-buffered frag-linear LDS;
// v_mfma_f32_32x32x16_bf16, 24 MFMA/step, ceiling 2495 TF (vs 2075 16x16).
// grid 2048: pt = blk&255, ct = blk>>8 -> 8 ct-siblings of a pt share one XCD.
__launch_bounds__(256, 3)
__global__ void k_dist(const short* __restrict__ Xh, const short* __restrict__ Xl,
                       const short* __restrict__ Eh, const short* __restrict__ El,
                       const float* __restrict__ e2, unsigned long long* __restrict__ win) {
    __shared__ __align__(16) short Bs[2][8192];   // [buf][16 frags x 512 shorts]
    __shared__ float sv[2][128];
    __shared__ int   si[2][128];

    const int tid = threadIdx.x;
    const int pt = blockIdx.x & 255;
    const int ct = blockIdx.x >> 8;
    const int n0 = pt * 128;
    const int c0 = ct * 128;

    const int w = tid >> 6, lane = tid & 63;
    const int wr = w >> 1, wc = w & 1;              // wave covers pts wr*64, codes wc*64
    const int l31 = lane & 31, lh = lane >> 5;

    f32x16 acc[2][2];
    #pragma unroll
    for (int i = 0; i < 2; ++i)
        #pragma unroll
        for (int j = 0; j < 2; ++j)
            #pragma unroll
            for (int e = 0; e < 16; ++e) acc[i][j][e] = 0.f;

    // A: frag offset = (pt*4 + wr*2 + i2)*8192 + (t*2+kf)*512; lane offset 16B.
    const short* Ahb = Xh + (pt * 4 + wr * 2) * 8192 + lane * 8;
    const short* Alb = Xl + (pt * 4 + wr * 2) * 8192 + lane * 8;
    // B staging: wave w stages frags (cb = (w&1)*2 + cb_off, kf) from array
    // (w<2 ? Eh : El) as 4 contiguous 1KB frag copies into LDS slot cb*2+kf
    // (+8 slots for El). LDS image == global frag bytes (frag-linear).
    const short* Ebase = (w < 2 ? Eh : El) + (ct * 4 + (w & 1) * 2) * 8192 + lane * 8;
    char* Bd0 = (char*)&Bs[0][0] + ((w >> 1) * 8 + (w & 1) * 4) * 1024;
    char* Bd1 = (char*)&Bs[1][0] + ((w >> 1) * 8 + (w & 1) * 4) * 1024;

    #define STAGE_B(buf, tt) do {                                     \
        char* d_ = (buf) ? Bd1 : Bd0;                                 \
        const short* s_ = Ebase + (tt) * 1024;                        \
        gload16(s_,              d_);                                 \
        gload16(s_ + 512,        d_ + 1024);                          \
        gload16(s_ + 8192,       d_ + 2048);                          \
        gload16(s_ + 8192 + 512, d_ + 3072);                          \
    } while (0)

    short8 ah[2][4], al[4];
    STAGE_B(0, 0);
    __builtin_amdgcn_sched_barrier(0);             // pin: B(0) issued before ah(0)
    #pragma unroll
    for (int f = 0; f < 4; ++f)   // f = i2*2+kf
        ah[0][f] = *reinterpret_cast<const short8*>(Ahb + (f >> 1) * 8192 + (f & 1) * 512);
    asm volatile("s_waitcnt vmcnt(4)" ::: "memory");   // own B(0) landed; ah(0) flying
    __builtin_amdgcn_s_barrier();
    __builtin_amdgcn_sched_barrier(0);

    #pragma unroll
    for (int t = 0; t < 8; ++t) {
        const int cur = t & 1;
        // B-high frags for this wave's codes: slot = (wc*2+j2)*2+kf = wc*4+f
        short8 bh[4];
        #pragma unroll
        for (int f = 0; f < 4; ++f)
            bh[f] = *(const short8*)&Bs[cur][(wc * 4 + f) * 512 + lane * 8];
        // al(t) (consumed in lh pass) then next B stage — both must complete
        // at this iteration's vmcnt(4); ah(t+1) must be issued after them.
        #pragma unroll
        for (int f = 0; f < 4; ++f)
            al[f] = *reinterpret_cast<const short8*>(Alb + (f >> 1) * 8192 + (t * 2 + (f & 1)) * 512);
        if (t < 7) STAGE_B(cur ^ 1, t + 1);

        __builtin_amdgcn_s_setprio(1);
        #pragma unroll
        for (int i2 = 0; i2 < 2; ++i2)          // hh
            #pragma unroll
            for (int j2 = 0; j2 < 2; ++j2)
                #pragma unroll
                for (int kf = 0; kf < 2; ++kf)
                    acc[i2][j2] = __builtin_amdgcn_mfma_f32_32x32x16_bf16(
                        ah[cur][i2 * 2 + kf], bh[j2 * 2 + kf], acc[i2][j2], 0, 0, 0);
        #pragma unroll
        for (int i2 = 0; i2 < 2; ++i2)          // lh
            #pragma unroll
            for (int j2 = 0; j2 < 2; ++j2)
                #pragma unroll
                for (int kf = 0; kf < 2; ++kf)
                    acc[i2][j2] = __builtin_amdgcn_mfma_f32_32x32x16_bf16(
                        al[i2 * 2 + kf], bh[j2 * 2 + kf], acc[i2][j2], 0, 0, 0);
        __builtin_amdgcn_s_setprio(0);
        if (t < 7) {
            __builtin_amdgcn_sched_barrier(0);  // pin: al+B(t+1) issued before ah(t+1)
            #pragma unroll
            for (int f = 0; f < 4; ++f)         // ah(t+1): full-cluster + barrier cover
                ah[cur ^ 1][f] = *reinterpret_cast<const short8*>(
                    Ahb + (f >> 1) * 8192 + ((t + 1) * 2 + (f & 1)) * 512);
        }
        short8 bl[4];
        #pragma unroll
        for (int f = 0; f < 4; ++f)
            bl[f] = *(const short8*)&Bs[cur][(8 + wc * 4 + f) * 512 + lane * 8];
        __builtin_amdgcn_s_setprio(1);
        #pragma unroll
        for (int i2 = 0; i2 < 2; ++i2)          // hl
            #pragma unroll
            for (int j2 = 0; j2 < 2; ++j2)
                #pragma unroll
                for (int kf = 0; kf < 2; ++kf)
                    acc[i2][j2] = __builtin_amdgcn_mfma_f32_32x32x16_bf16(
                        ah[cur][i2 * 2 + kf], bl[j2 * 2 + kf], acc[i2][j2], 0, 0, 0);
        __builtin_amdgcn_s_setprio(0);
        if (t < 7) {
            // own B(t+1) landed BEFORE releasing readers; ah(t+1) stays in flight
            asm volatile("s_waitcnt vmcnt(4)" ::: "memory");
            __builtin_amdgcn_s_barrier();
            __builtin_amdgcn_sched_barrier(0);
        }
    }
    #undef STAGE_B

    // dist = e2[code] - 2*dot ; 32x32 C/D: col(code)=lane&31,
    // row(pt)=(r&3)+8*(r>>2)+4*(lane>>5)  [HW-verified m74/m101]
    float ecol[2];
    ecol[0] = e2[c0 + wc * 64 + l31];
    ecol[1] = e2[c0 + wc * 64 + 32 + l31];
    const int codeb = c0 + wc * 64 + l31;

    #pragma unroll
    for (int i2 = 0; i2 < 2; ++i2) {
        #pragma unroll
        for (int r = 0; r < 16; ++r) {
            float d0 = fmaf(-2.f, acc[i2][0][r], ecol[0]);
            float d1 = fmaf(-2.f, acc[i2][1][r], ecol[1]);
            float best = d0; int bi = codeb;                    // j2=0 first -> first-min
            if (d1 < best) { best = d1; bi = codeb + 32; }
            #pragma unroll
            for (int m = 1; m < 32; m <<= 1) {                  // 32-lane half-wave reduce
                float ov = __shfl_xor(best, m);
                int   oi = __shfl_xor(bi, m);
                if (ov < best || (ov == best && oi < bi)) { best = ov; bi = oi; }
            }
            if (l31 == 0) {
                int p = wr * 64 + i2 * 32 + (r & 3) + 8 * (r >> 2) + 4 * lh;
                sv[wc][p] = best; si[wc][p] = bi;
            }
        }
    }
    __syncthreads();
    if (tid < 128) {
        float v0 = sv[0][tid]; int i0 = si[0][tid];
        float v1 = sv[1][tid]; int i1 = si[1][tid];
        if (v1 < v0) { v0 = v1; i0 = i1; }          // tie -> wc0 = smaller codes
        atomicMin(win + n0 + tid, pack_di(v0, i0)); // global argmin, no round-trip
    }
}

// ---- output: gather winner rows + write q/st/idx. grid 2048 (c-half split). ----
__global__ void k_out(const float* __restrict__ z, const float* __restrict__ emb,
                      const unsigned long long* __restrict__ win,
                      float* __restrict__ out) {
    __shared__ float Q[32][129];                    // [hw_local][c_half], 16.5KB
    __shared__ int sbi[32];
    int blk = blockIdx.x;
    int n0 = (blk >> 1) * 32;
    int ch = blk & 1;                               // c in [ch*128, ch*128+128)
    int tid = threadIdx.x;
    if (tid < 32) {
        int n = n0 + tid;
        int bi = (int)(unsigned)(win[n] & 0xFFFFFFFFull);
        sbi[tid] = bi;
        if (ch == 0) out[2 * QSZ + n] = (float)bi;  // idx as float
    }
    __syncthreads();
    {   // gather: 8 lanes x float4 x 4 j cover the 512B half-row per point
        int pt = tid >> 3, co = tid & 7;
        const float* ep = emb + sbi[pt] * DIM + ch * 128;
        #pragma unroll
        for (int j = 0; j < 4; ++j) {
            int c = j * 32 + co * 4;
            float4 v = *reinterpret_cast<const float4*>(ep + c);
            Q[pt][c] = v.x; Q[pt][c + 1] = v.y; Q[pt][c + 2] = v.z; Q[pt][c + 3] = v.w;
        }
    }
    __syncthreads();
    int hq = tid & 7, cr = tid >> 3;                // 8x16B = 128B runs per c-row
    int b = n0 >> 10, hw0 = (n0 & 1023) + hq * 4;
    #pragma unroll
    for (int it = 0; it < 4; ++it) {
        int cl = it * 32 + cr;                      // local c within half
        int c  = ch * 128 + cl;
        int off = b * CHW + c * HWSZ + hw0;
        float4 zv = *reinterpret_cast<const float4*>(z + off);
        float4 q = make_float4(Q[hq * 4 + 0][cl], Q[hq * 4 + 1][cl],
                               Q[hq * 4 + 2][cl], Q[hq * 4 + 3][cl]);
        *reinterpret_cast<float4*>(out + off) = q;
        float4 st = make_float4((q.x - zv.x) + zv.x, (q.y - zv.y) + zv.y,
                                (q.z - zv.z) + zv.z, (q.w - zv.w) + zv.w);
        *reinterpret_cast<float4*>(out + QSZ + off) = st;
    }
}

extern "C" void kernel_launch(void* const* d_in, const int* in_sizes, int n_in,
                              void* d_out, int out_size, void* d_ws, size_t ws_size,
                              hipStream_t stream) {
    const float* z   = (const float*)d_in[0];
    const float* emb = (const float*)d_in[1];
    float* out = (float*)d_out;
    float* ws  = (float*)d_ws;

    // ws layout (floats): Eh[0,131072) El[131072,262144) e2[262144,263168)
    //                     win[263168, 263168+65536) as u64 (256KB, 8B-aligned)
    short* Eh   = (short*)ws;
    short* El   = (short*)(ws + 131072);
    float* e2   = ws + 262144;
    unsigned long long* win = (unsigned long long*)(ws + 263168);

    // big X arrays live in d_out's q/st region (fully overwritten by k_out later)
    short* Xh = (short*)out;                 // 16.8 MB
    short* Xl = (short*)(out + 4194304);     // 16.8 MB

    hipLaunchKernelGGL(k_prep, dim3(2304), dim3(256), 0, stream, z, emb, Xh, Xl, Eh, El, e2, win);
    hipLaunchKernelGGL(k_dist, dim3(2048), dim3(256), 0, stream, Xh, Xl, Eh, El, e2, win);
    hipLaunchKernelGGL(k_out,  dim3(2048), dim3(256), 0, stream, z, emb, win, out);
}

// Round 10
// 172.970 us; speedup vs baseline: 1.1259x; 1.1259x over previous
//
#include <hip/hip_runtime.h>

#define NPTS   32768
#define NCODES 1024
#define DIM    256
#define HWSZ   1024
#define CHW    (DIM*HWSZ)      // 262144
#define QSZ    8388608         // B*C*H*W

typedef __attribute__((ext_vector_type(8))) short short8;   // 8 bf16 = 4 VGPRs
typedef __attribute__((ext_vector_type(4))) float f32x4;

__device__ __forceinline__ unsigned bf16_rne(float f) {
    unsigned u = __float_as_uint(f);
    return (u + 0x7fffu + ((u >> 16) & 1u)) >> 16;
}

// pack (dist, code) into a monotone u64 key: smaller dist first, then smaller code.
__device__ __forceinline__ unsigned long long pack_di(float d, int code) {
    unsigned u = __float_as_uint(d);
    unsigned key = u ^ ((unsigned)((int)u >> 31) | 0x80000000u);
    return ((unsigned long long)key << 32) | (unsigned)code;
}

// Frag-major layout (16x16x32): element (row n, chan c) lives at
//   [n>>7][(n>>6)&1][c>>5][(n>>4)&3][(c>>3)&3][n&15][c&7]
// so an MFMA frag (fixed n-block, t, i) is one contiguous 1KB run with
// lane (m16,quad) at base + lane*16B. Same formula serves X and E.
// Verified end-to-end in R6 (absmax 0).
__device__ __forceinline__ int fmoff(int n, int c) {
    return ((((((n >> 7) * 2 + ((n >> 6) & 1)) * 8 + (c >> 5)) * 4 + ((n >> 4) & 3)) * 4
             + ((c >> 3) & 3)) * 16 + (n & 15)) * 8 + (c & 7);
}

// ---- fused prep: blocks 0..2047 = z -> Xh/Xl transpose+split (c-half per block);
//                  blocks 2048..2303 = emb -> Eh/El + e2, plus win[] init ----
__global__ void k_prep(const float* __restrict__ z, const float* __restrict__ emb,
                       short* __restrict__ Xh, short* __restrict__ Xl,
                       short* __restrict__ Eh, short* __restrict__ El,
                       float* __restrict__ e2, unsigned long long* __restrict__ win) {
    int tid = threadIdx.x;
    if (blockIdx.x >= 2048) {
        int eb = blockIdx.x - 2048;
        // init packed-argmin array (runs before k_dist by stream order)
        int widx = eb * 256 + tid;
        if (widx < NPTS) win[widx] = ~0ull;
        // --- emb row -> Eh/El bf16 split + e2 (fp64). 1 wave per row. ---
        int lane = tid & 63, w = tid >> 6;
        int k = eb * 4 + w;
        const float4 v = *reinterpret_cast<const float4*>(emb + k * DIM + lane * 4);
        float f[4] = {v.x, v.y, v.z, v.w};
        short h[4], l[4];
        double s = 0.0;
        #pragma unroll
        for (int i = 0; i < 4; ++i) {
            unsigned hb = bf16_rne(f[i]);
            float hf = __uint_as_float(hb << 16);
            h[i] = (short)hb;
            l[i] = (short)bf16_rne(f[i] - hf);
            s += (double)f[i] * f[i];
        }
        int eoff = fmoff(k, lane * 4);     // (c&7) in {0,4} -> 8B-aligned
        *reinterpret_cast<short4*>(Eh + eoff) = make_short4(h[0], h[1], h[2], h[3]);
        *reinterpret_cast<short4*>(El + eoff) = make_short4(l[0], l[1], l[2], l[3]);
        #pragma unroll
        for (int m = 32; m >= 1; m >>= 1) s += __shfl_xor(s, m);
        if (lane == 0) e2[k] = (float)s;
        return;
    }
    // --- z (b,c,hw) -> Xh/Xl frag-major bf16 hi/lo; 16B stores ---
    __shared__ float T[64][33];          // [c_local][hw_local], pad: <=2-way banks
    int blk = blockIdx.x;
    int b   = blk >> 6;
    int rem = blk & 63;
    int ht  = rem >> 1;
    int ch  = rem & 1;                   // c-half: cc in {2ch, 2ch+1}
    int hw0 = ht * 32;
    int n0  = b * HWSZ + hw0;
    int hq = tid & 7, cr = tid >> 3;     // read map: 32 c-rows x 8 float4 lanes
    int wp = tid >> 3, wc = tid & 7;     // write map: 32 points x 8 channel-octets
    const float* zp = z + b * CHW;
    #pragma unroll
    for (int cc2 = 0; cc2 < 2; ++cc2) {
        int c0 = (ch * 2 + cc2) * 64;
        if (cc2) __syncthreads();
        #pragma unroll
        for (int p = 0; p < 2; ++p) {
            int c = p * 32 + cr;
            float4 v = *reinterpret_cast<const float4*>(zp + (c0 + c) * HWSZ + hw0 + hq * 4);
            T[c][hq * 4 + 0] = v.x; T[c][hq * 4 + 1] = v.y;
            T[c][hq * 4 + 2] = v.z; T[c][hq * 4 + 3] = v.w;
        }
        __syncthreads();
        short8 hv, lv;
        #pragma unroll
        for (int k = 0; k < 8; ++k) {
            float f = T[wc * 8 + k][wp];
            unsigned hb = bf16_rne(f);
            float hf = __uint_as_float(hb << 16);
            hv[k] = (short)hb;
            lv[k] = (short)bf16_rne(f - hf);
        }
        int off = fmoff(n0 + wp, c0 + wc * 8);   // octet-aligned -> 16B store
        *reinterpret_cast<short8*>(Xh + off) = hv;
        *reinterpret_cast<short8*>(Xl + off) = lv;
    }
}

// ---- zero-LDS frag-major GEMM + argmin, HK-regime: 2 waves/SIMD + deep ILP ----
// Round-15 = R6 core + explicit 2-deep register pipeline. All 16 frags of
// step t+1 are issued BEFORE step t's 48-MFMA cluster, so every load has a
// full ~930-cycle cluster of latency cover (>= cold HBM ~900, >> warm L2).
// Register budget: 128 VGPR operands (2 bufs x 16 frags) + 64 AGPR acc +
// addr ~ 204 unified -> fits 2 waves/SIMD (launch_bounds 256,2), no spill.
// No barriers, no LDS staging, no waitcnt management (compiler emits counted
// vmcnt before first use of each buffer). cur = t&1 is compile-time under
// full unroll. This is HipKittens' occupancy point (TLP -> register ILP).
// grid 2048: pt = blk&255, ct = blk>>8 -> 8 ct-siblings of a pt share one XCD.
__launch_bounds__(256, 2)
__global__ void k_dist(const short* __restrict__ Xh, const short* __restrict__ Xl,
                       const short* __restrict__ Eh, const short* __restrict__ El,
                       const float* __restrict__ e2, unsigned long long* __restrict__ win) {
    __shared__ float sv[2][128];
    __shared__ int   si[2][128];

    const int tid = threadIdx.x;
    const int pt = blockIdx.x & 255;
    const int ct = blockIdx.x >> 8;
    const int n0 = pt * 128;
    const int c0 = ct * 128;

    const int w = tid >> 6, lane = tid & 63;
    const int wr = w >> 1, wc = w & 1;              // wave covers pts wr*64, codes wc*64
    const int m16 = lane & 15, quad = lane >> 4;

    f32x4 acc[4][4];
    #pragma unroll
    for (int i = 0; i < 4; ++i)
        #pragma unroll
        for (int j = 0; j < 4; ++j) acc[i][j] = (f32x4){0.f, 0.f, 0.f, 0.f};

    // per-(n-block) frag bases: 64 rows x 256 c = 16384 shorts; frag stride
    // within: t*2048 + i*512; lane offset lane*8 shorts = 16B.
    const short* Ahb = Xh + (pt * 2 + wr) * 16384 + lane * 8;
    const short* Alb = Xl + (pt * 2 + wr) * 16384 + lane * 8;
    const short* Bhb = Eh + (ct * 2 + wc) * 16384 + lane * 8;
    const short* Blb = El + (ct * 2 + wc) * 16384 + lane * 8;

    short8 ah[2][4], al[2][4], bh[2][4], bl[2][4];

    // prologue: fill buffer 0 (t=0)
    #pragma unroll
    for (int i = 0; i < 4; ++i) {
        ah[0][i] = *reinterpret_cast<const short8*>(Ahb + i * 512);
        al[0][i] = *reinterpret_cast<const short8*>(Alb + i * 512);
        bh[0][i] = *reinterpret_cast<const short8*>(Bhb + i * 512);
        bl[0][i] = *reinterpret_cast<const short8*>(Blb + i * 512);
    }

    #pragma unroll
    for (int t = 0; t < 8; ++t) {
        const int cur = t & 1;
        const int nxt = cur ^ 1;
        if (t < 7) {                       // issue t+1's 16 loads BEFORE the cluster
            const int to = (t + 1) * 2048;
            #pragma unroll
            for (int i = 0; i < 4; ++i) {
                ah[nxt][i] = *reinterpret_cast<const short8*>(Ahb + to + i * 512);
                al[nxt][i] = *reinterpret_cast<const short8*>(Alb + to + i * 512);
                bh[nxt][i] = *reinterpret_cast<const short8*>(Bhb + to + i * 512);
                bl[nxt][i] = *reinterpret_cast<const short8*>(Blb + to + i * 512);
            }
        }
        __builtin_amdgcn_s_setprio(1);
        #pragma unroll
        for (int i = 0; i < 4; ++i)
            #pragma unroll
            for (int j = 0; j < 4; ++j)
                acc[i][j] = __builtin_amdgcn_mfma_f32_16x16x32_bf16(ah[cur][i], bh[cur][j], acc[i][j], 0, 0, 0);
        #pragma unroll
        for (int i = 0; i < 4; ++i)
            #pragma unroll
            for (int j = 0; j < 4; ++j)
                acc[i][j] = __builtin_amdgcn_mfma_f32_16x16x32_bf16(al[cur][i], bh[cur][j], acc[i][j], 0, 0, 0);
        #pragma unroll
        for (int i = 0; i < 4; ++i)
            #pragma unroll
            for (int j = 0; j < 4; ++j)
                acc[i][j] = __builtin_amdgcn_mfma_f32_16x16x32_bf16(ah[cur][i], bl[cur][j], acc[i][j], 0, 0, 0);
        __builtin_amdgcn_s_setprio(0);
    }

    // dist = e2[code] - 2*dot ; C/D layout: col=lane&15 (code), row=quad*4+reg (pt)
    float ecol[4];
    #pragma unroll
    for (int j = 0; j < 4; ++j) ecol[j] = e2[c0 + wc * 64 + j * 16 + m16];

    #pragma unroll
    for (int i = 0; i < 4; ++i) {
        #pragma unroll
        for (int rr = 0; rr < 4; ++rr) {
            float best = 3.4e38f; int bi = 0;
            #pragma unroll
            for (int j = 0; j < 4; ++j) {           // j ascending -> code ascending
                float d = fmaf(-2.f, acc[i][j][rr], ecol[j]);
                int code = c0 + wc * 64 + j * 16 + m16;
                if (d < best) { best = d; bi = code; }
            }
            #pragma unroll
            for (int m = 1; m < 16; m <<= 1) {      // 16 lanes hold 16 codes of this pt
                float ov = __shfl_xor(best, m);
                int   oi = __shfl_xor(bi, m);
                if (ov < best || (ov == best && oi < bi)) { best = ov; bi = oi; }
            }
            if (m16 == 0) {
                int p = wr * 64 + i * 16 + quad * 4 + rr;
                sv[wc][p] = best; si[wc][p] = bi;
            }
        }
    }
    __syncthreads();
    if (tid < 128) {
        float v0 = sv[0][tid]; int i0 = si[0][tid];
        float v1 = sv[1][tid]; int i1 = si[1][tid];
        if (v1 < v0) { v0 = v1; i0 = i1; }          // tie -> wc0 = smaller codes
        atomicMin(win + n0 + tid, pack_di(v0, i0)); // global argmin, no round-trip
    }
}

// ---- output: gather winner rows + write q/st/idx. grid 2048 (c-half split). ----
__global__ void k_out(const float* __restrict__ z, const float* __restrict__ emb,
                      const unsigned long long* __restrict__ win,
                      float* __restrict__ out) {
    __shared__ float Q[32][129];                    // [hw_local][c_half], 16.5KB
    __shared__ int sbi[32];
    int blk = blockIdx.x;
    int n0 = (blk >> 1) * 32;
    int ch = blk & 1;                               // c in [ch*128, ch*128+128)
    int tid = threadIdx.x;
    if (tid < 32) {
        int n = n0 + tid;
        int bi = (int)(unsigned)(win[n] & 0xFFFFFFFFull);
        sbi[tid] = bi;
        if (ch == 0) out[2 * QSZ + n] = (float)bi;  // idx as float
    }
    __syncthreads();
    {   // gather: 8 lanes x float4 x 4 j cover the 512B half-row per point
        int pt = tid >> 3, co = tid & 7;
        const float* ep = emb + sbi[pt] * DIM + ch * 128;
        #pragma unroll
        for (int j = 0; j < 4; ++j) {
            int c = j * 32 + co * 4;
            float4 v = *reinterpret_cast<const float4*>(ep + c);
            Q[pt][c] = v.x; Q[pt][c + 1] = v.y; Q[pt][c + 2] = v.z; Q[pt][c + 3] = v.w;
        }
    }
    __syncthreads();
    int hq = tid & 7, cr = tid >> 3;                // 8x16B = 128B runs per c-row
    int b = n0 >> 10, hw0 = (n0 & 1023) + hq * 4;
    #pragma unroll
    for (int it = 0; it < 4; ++it) {
        int cl = it * 32 + cr;                      // local c within half
        int c  = ch * 128 + cl;
        int off = b * CHW + c * HWSZ + hw0;
        float4 zv = *reinterpret_cast<const float4*>(z + off);
        float4 q = make_float4(Q[hq * 4 + 0][cl], Q[hq * 4 + 1][cl],
                               Q[hq * 4 + 2][cl], Q[hq * 4 + 3][cl]);
        *reinterpret_cast<float4*>(out + off) = q;
        float4 st = make_float4((q.x - zv.x) + zv.x, (q.y - zv.y) + zv.y,
                                (q.z - zv.z) + zv.z, (q.w - zv.w) + zv.w);
        *reinterpret_cast<float4*>(out + QSZ + off) = st;
    }
}

extern "C" void kernel_launch(void* const* d_in, const int* in_sizes, int n_in,
                              void* d_out, int out_size, void* d_ws, size_t ws_size,
                              hipStream_t stream) {
    const float* z   = (const float*)d_in[0];
    const float* emb = (const float*)d_in[1];
    float* out = (float*)d_out;
    float* ws  = (float*)d_ws;

    // ws layout (floats): Eh[0,131072) El[131072,262144) e2[262144,263168)
    //                     win[263168, 263168+65536) as u64 (256KB, 8B-aligned)
    short* Eh   = (short*)ws;
    short* El   = (short*)(ws + 131072);
    float* e2   = ws + 262144;
    unsigned long long* win = (unsigned long long*)(ws + 263168);

    // big X arrays live in d_out's q/st region (fully overwritten by k_out later)
    short* Xh = (short*)out;                 // 16.8 MB
    short* Xl = (short*)(out + 4194304);     // 16.8 MB

    hipLaunchKernelGGL(k_prep, dim3(2304), dim3(256), 0, stream, z, emb, Xh, Xl, Eh, El, e2, win);
    hipLaunchKernelGGL(k_dist, dim3(2048), dim3(256), 0, stream, Xh, Xl, Eh, El, e2, win);
    hipLaunchKernelGGL(k_out,  dim3(2048), dim3(256), 0, stream, z, emb, win, out);
}

// Round 11
// 162.208 us; speedup vs baseline: 1.2006x; 1.0663x over previous
//
#include <hip/hip_runtime.h>

#define NPTS   32768
#define NCODES 1024
#define DIM    256
#define HWSZ   1024
#define CHW    (DIM*HWSZ)      // 262144
#define QSZ    8388608         // B*C*H*W

typedef __attribute__((ext_vector_type(8))) short short8;   // 8 bf16 = 4 VGPRs
typedef __attribute__((ext_vector_type(4))) float f32x4;

__device__ __forceinline__ unsigned bf16_rne(float f) {
    unsigned u = __float_as_uint(f);
    return (u + 0x7fffu + ((u >> 16) & 1u)) >> 16;
}

// pack (dist, code) into a monotone u64 key: smaller dist first, then smaller code.
__device__ __forceinline__ unsigned long long pack_di(float d, int code) {
    unsigned u = __float_as_uint(d);
    unsigned key = u ^ ((unsigned)((int)u >> 31) | 0x80000000u);
    return ((unsigned long long)key << 32) | (unsigned)code;
}

// Frag-major layout (16x16x32), verified end-to-end in R6 (absmax 0):
//   (row n, chan c) -> [n>>7][(n>>6)&1][c>>5][(n>>4)&3][(c>>3)&3][n&15][c&7]
// An MFMA frag is one contiguous 1KB run; lane (m16,quad) at base + lane*16B.
__device__ __forceinline__ int fmoff(int n, int c) {
    return ((((((n >> 7) * 2 + ((n >> 6) & 1)) * 8 + (c >> 5)) * 4 + ((n >> 4) & 3)) * 4
             + ((c >> 3) & 3)) * 16 + (n & 15)) * 8 + (c & 7);
}

// ---- emb -> Eh/El frag-major bf16 split + e2 (fp64 row norms). grid 256. ----
__global__ void k_emb(const float* __restrict__ emb,
                      short* __restrict__ Eh, short* __restrict__ El,
                      float* __restrict__ e2) {
    int tid = threadIdx.x;
    int lane = tid & 63, w = tid >> 6;
    int k = blockIdx.x * 4 + w;
    const float4 v = *reinterpret_cast<const float4*>(emb + k * DIM + lane * 4);
    float f[4] = {v.x, v.y, v.z, v.w};
    short h[4], l[4];
    double s = 0.0;
    #pragma unroll
    for (int i = 0; i < 4; ++i) {
        unsigned hb = bf16_rne(f[i]);
        float hf = __uint_as_float(hb << 16);
        h[i] = (short)hb;
        l[i] = (short)bf16_rne(f[i] - hf);
        s += (double)f[i] * f[i];
    }
    int eoff = fmoff(k, lane * 4);     // (c&7) in {0,4} -> 8B-aligned
    *reinterpret_cast<short4*>(Eh + eoff) = make_short4(h[0], h[1], h[2], h[3]);
    *reinterpret_cast<short4*>(El + eoff) = make_short4(l[0], l[1], l[2], l[3]);
    #pragma unroll
    for (int m = 32; m >= 1; m >>= 1) s += __shfl_xor(s, m);
    if (lane == 0) e2[k] = (float)s;
}

// ---- fused: z-convert (once) + full-codebook GEMM (ct-loop) + argmin ----
// Round-16: grid 256 = 1 block/CU; block owns a 128-pt tile end-to-end.
// Phase 1: z -> frag-linear Ah/Al in LDS (128 KB), conversion done ONCE per
// point (R8's failure was 8x redundant conversion; this removes it).
// Phase 2: for ct = 0..7: stream E via R6-verified frag-major direct L2
// loads (no LDS staging, no barriers, no vmcnt management), 48 MFMA/step,
// per-thread running argmin across cts (strict < over ascending ct = exact
// first-min semantics). Deletes the 67MB X round-trip, k_prep's z pass,
// all atomics, and the win-init.
// Pipe budget/CU: MFMA 20.6us, LDS-read 10us, E-from-L2 15us -> MFMA-bound.
__launch_bounds__(256, 1)
__global__ void k_main(const float* __restrict__ z,
                       const short* __restrict__ Eh, const short* __restrict__ El,
                       const float* __restrict__ e2,
                       unsigned long long* __restrict__ win) {
    __shared__ __align__(16) short Ah_lds[32768];   // 64 KB [128 pts][256 k] frag-linear
    __shared__ __align__(16) short Al_lds[32768];   // 64 KB
    __shared__ float T[64][33];                     // 8.4 KB transpose buffer
    __shared__ float sv[2][128];
    __shared__ int   si[2][128];

    const int tid = threadIdx.x;
    const int n0 = blockIdx.x * 128;
    const int b = n0 >> 10, hw0 = n0 & 1023;

    // ---- phase 1: z (c, hw) -> Ah/Al bf16 hi/lo, frag-linear ----
    {
        int hq = tid & 7, cr = tid >> 3;     // read map: 32 c-rows x 8 float4 lanes
        int wp = tid >> 3, wcc = tid & 7;    // write map: 32 points x 8 channel-octets
        const float* zp = z + b * CHW;
        for (int ht = 0; ht < 4; ++ht) {     // 4 stripes of 32 hw
            int hwb = hw0 + ht * 32;
            for (int cc = 0; cc < 4; ++cc) { // 4 chunks of 64 c
                int c0 = cc * 64;
                __syncthreads();             // T readers of prev chunk done
                #pragma unroll
                for (int p = 0; p < 2; ++p) {
                    int c = p * 32 + cr;
                    float4 v = *reinterpret_cast<const float4*>(zp + (c0 + c) * HWSZ + hwb + hq * 4);
                    T[c][hq * 4 + 0] = v.x; T[c][hq * 4 + 1] = v.y;
                    T[c][hq * 4 + 2] = v.z; T[c][hq * 4 + 3] = v.w;
                }
                __syncthreads();
                short8 hv, lv;
                #pragma unroll
                for (int k = 0; k < 8; ++k) {
                    float f = T[wcc * 8 + k][wp];
                    unsigned hb = bf16_rne(f);
                    float hf = __uint_as_float(hb << 16);
                    hv[k] = (short)hb;
                    lv[k] = (short)bf16_rne(f - hf);
                }
                int off = fmoff(ht * 32 + wp, c0 + wcc * 8);   // n_local < 128
                *reinterpret_cast<short8*>(&Ah_lds[off]) = hv;
                *reinterpret_cast<short8*>(&Al_lds[off]) = lv;
            }
        }
    }
    __syncthreads();                          // A tile fully built

    // ---- phase 2: GEMM over all 8 ct-tiles + running argmin ----
    const int w = tid >> 6, lane = tid & 63;
    const int wr = w >> 1, wc = w & 1;        // wave covers pts wr*64, codes wc*64
    const int m16 = lane & 15, quad = lane >> 4;

    const short* AhL = Ah_lds + wr * 16384 + lane * 8;
    const short* AlL = Al_lds + wr * 16384 + lane * 8;

    float best[4][4]; int bidx[4][4];
    #pragma unroll
    for (int i = 0; i < 4; ++i)
        #pragma unroll
        for (int rr = 0; rr < 4; ++rr) { best[i][rr] = 3.4e38f; bidx[i][rr] = 0; }

    for (int ct = 0; ct < 8; ++ct) {
        const short* Bhb = Eh + (ct * 2 + wc) * 16384 + lane * 8;
        const short* Blb = El + (ct * 2 + wc) * 16384 + lane * 8;

        f32x4 acc[4][4];
        #pragma unroll
        for (int i = 0; i < 4; ++i)
            #pragma unroll
            for (int j = 0; j < 4; ++j) acc[i][j] = (f32x4){0.f, 0.f, 0.f, 0.f};

        #pragma unroll
        for (int t = 0; t < 8; ++t) {
            const int to = t * 2048;
            short8 ah[4], al[4], bh[4], bl[4];
            #pragma unroll
            for (int i = 0; i < 4; ++i) {
                ah[i] = *reinterpret_cast<const short8*>(AhL + to + i * 512);
                al[i] = *reinterpret_cast<const short8*>(AlL + to + i * 512);
            }
            #pragma unroll
            for (int j = 0; j < 4; ++j) {
                bh[j] = *reinterpret_cast<const short8*>(Bhb + to + j * 512);
                bl[j] = *reinterpret_cast<const short8*>(Blb + to + j * 512);
            }
            __builtin_amdgcn_s_setprio(1);
            #pragma unroll
            for (int i = 0; i < 4; ++i)
                #pragma unroll
                for (int j = 0; j < 4; ++j)
                    acc[i][j] = __builtin_amdgcn_mfma_f32_16x16x32_bf16(ah[i], bh[j], acc[i][j], 0, 0, 0);
            #pragma unroll
            for (int i = 0; i < 4; ++i)
                #pragma unroll
                for (int j = 0; j < 4; ++j)
                    acc[i][j] = __builtin_amdgcn_mfma_f32_16x16x32_bf16(al[i], bh[j], acc[i][j], 0, 0, 0);
            #pragma unroll
            for (int i = 0; i < 4; ++i)
                #pragma unroll
                for (int j = 0; j < 4; ++j)
                    acc[i][j] = __builtin_amdgcn_mfma_f32_16x16x32_bf16(ah[i], bl[j], acc[i][j], 0, 0, 0);
            __builtin_amdgcn_s_setprio(0);
        }

        // fold this ct-tile into the running argmin (ct ascending -> first-min)
        const int c0 = ct * 128;
        float e0[4];
        #pragma unroll
        for (int j = 0; j < 4; ++j) e0[j] = e2[c0 + wc * 64 + j * 16 + m16];
        #pragma unroll
        for (int i = 0; i < 4; ++i)
            #pragma unroll
            for (int rr = 0; rr < 4; ++rr)
                #pragma unroll
                for (int j = 0; j < 4; ++j) {       // j ascending -> code ascending
                    float d = fmaf(-2.f, acc[i][j][rr], e0[j]);
                    if (d < best[i][rr]) {
                        best[i][rr] = d;
                        bidx[i][rr] = c0 + wc * 64 + j * 16 + m16;
                    }
                }
    }

    // ---- final reduce: 16 lanes hold 16 code-columns of each pt ----
    #pragma unroll
    for (int i = 0; i < 4; ++i) {
        #pragma unroll
        for (int rr = 0; rr < 4; ++rr) {
            float bv = best[i][rr]; int bi = bidx[i][rr];
            #pragma unroll
            for (int m = 1; m < 16; m <<= 1) {
                float ov = __shfl_xor(bv, m);
                int   oi = __shfl_xor(bi, m);
                if (ov < bv || (ov == bv && oi < bi)) { bv = ov; bi = oi; }
            }
            if (m16 == 0) {
                int p = wr * 64 + i * 16 + quad * 4 + rr;
                sv[wc][p] = bv; si[wc][p] = bi;
            }
        }
    }
    __syncthreads();
    if (tid < 128) {
        float v0 = sv[0][tid]; int i0 = si[0][tid];
        float v1 = sv[1][tid]; int i1 = si[1][tid];
        // codes interleave across wc halves per ct -> need explicit index tie-break
        if (v1 < v0 || (v1 == v0 && i1 < i0)) { v0 = v1; i0 = i1; }
        win[n0 + tid] = pack_di(v0, i0);            // plain store, no atomics
    }
}

// ---- output: gather winner rows + write q/st/idx. grid 2048 (c-half split). ----
__global__ void k_out(const float* __restrict__ z, const float* __restrict__ emb,
                      const unsigned long long* __restrict__ win,
                      float* __restrict__ out) {
    __shared__ float Q[32][129];                    // [hw_local][c_half], 16.5KB
    __shared__ int sbi[32];
    int blk = blockIdx.x;
    int n0 = (blk >> 1) * 32;
    int ch = blk & 1;                               // c in [ch*128, ch*128+128)
    int tid = threadIdx.x;
    if (tid < 32) {
        int n = n0 + tid;
        int bi = (int)(unsigned)(win[n] & 0xFFFFFFFFull);
        sbi[tid] = bi;
        if (ch == 0) out[2 * QSZ + n] = (float)bi;  // idx as float
    }
    __syncthreads();
    {   // gather: 8 lanes x float4 x 4 j cover the 512B half-row per point
        int pt = tid >> 3, co = tid & 7;
        const float* ep = emb + sbi[pt] * DIM + ch * 128;
        #pragma unroll
        for (int j = 0; j < 4; ++j) {
            int c = j * 32 + co * 4;
            float4 v = *reinterpret_cast<const float4*>(ep + c);
            Q[pt][c] = v.x; Q[pt][c + 1] = v.y; Q[pt][c + 2] = v.z; Q[pt][c + 3] = v.w;
        }
    }
    __syncthreads();
    int hq = tid & 7, cr = tid >> 3;                // 8x16B = 128B runs per c-row
    int b = n0 >> 10, hw0 = (n0 & 1023) + hq * 4;
    #pragma unroll
    for (int it = 0; it < 4; ++it) {
        int cl = it * 32 + cr;                      // local c within half
        int c  = ch * 128 + cl;
        int off = b * CHW + c * HWSZ + hw0;
        float4 zv = *reinterpret_cast<const float4*>(z + off);
        float4 q = make_float4(Q[hq * 4 + 0][cl], Q[hq * 4 + 1][cl],
                               Q[hq * 4 + 2][cl], Q[hq * 4 + 3][cl]);
        *reinterpret_cast<float4*>(out + off) = q;
        float4 st = make_float4((q.x - zv.x) + zv.x, (q.y - zv.y) + zv.y,
                                (q.z - zv.z) + zv.z, (q.w - zv.w) + zv.w);
        *reinterpret_cast<float4*>(out + QSZ + off) = st;
    }
}

extern "C" void kernel_launch(void* const* d_in, const int* in_sizes, int n_in,
                              void* d_out, int out_size, void* d_ws, size_t ws_size,
                              hipStream_t stream) {
    const float* z   = (const float*)d_in[0];
    const float* emb = (const float*)d_in[1];
    float* out = (float*)d_out;
    float* ws  = (float*)d_ws;

    // ws layout (floats): Eh[0,131072) El[131072,262144) e2[262144,263168)
    //                     win[263168, 263168+65536) as u64 (256KB, 8B-aligned)
    short* Eh   = (short*)ws;
    short* El   = (short*)(ws + 131072);
    float* e2   = ws + 262144;
    unsigned long long* win = (unsigned long long*)(ws + 263168);

    hipLaunchKernelGGL(k_emb,  dim3(256),  dim3(256), 0, stream, emb, Eh, El, e2);
    hipLaunchKernelGGL(k_main, dim3(256),  dim3(256), 0, stream, z, Eh, El, e2, win);
    hipLaunchKernelGGL(k_out,  dim3(2048), dim3(256), 0, stream, z, emb, win, out);
}